// Round 8
// baseline (535.173 us; speedup 1.0000x reference)
//
#include <hip/hip_runtime.h>
#include <hip/hip_bf16.h>
#include <stdint.h>

// LinearAttention_9569187136035 — round 12: revert gemm_bt to the round-7
// 128x128/BK=32 2-phase kernel (measured 69.2us/497TF on this shape vs
// 78.7us for the 256x256 8-phase port; multiple 32KB-LDS blocks per CU
// interleave barriers, which the single-block 8-phase cannot). Keep round-9
// fast converts, MFMA ctx_partial, outpre@2048. First time this combination
// is measured together.

typedef __bf16 bf16_t;
typedef __bf16 v8bf __attribute__((ext_vector_type(8)));
typedef __bf16 v4bf __attribute__((ext_vector_type(4)));
typedef float  v4f  __attribute__((ext_vector_type(4)));

#define NSPLIT 16

__device__ __forceinline__ void gl_lds16(const void* g, void* l) {
  __builtin_amdgcn_global_load_lds((const __attribute__((address_space(1))) void*)g,
                                   (__attribute__((address_space(3))) void*)l,
                                   16, 0, 0);
}

// ---- weights f32 -> bf16 (Wq,Wk,Wv,Wp -> 8MB ws region) ----
__global__ __launch_bounds__(256) void convert_w(
    const float* __restrict__ W0, const float* __restrict__ W1,
    const float* __restrict__ W2, const float* __restrict__ W3,
    bf16_t* __restrict__ dst)
{
  int g = blockIdx.x * 256 + threadIdx.x;      // 2048 blocks
  int seg = g >> 17;
  int off = (g & 131071) * 8;
  const float* s = (seg == 0 ? W0 : seg == 1 ? W1 : seg == 2 ? W2 : W3) + off;
  v4f a = *(const v4f*)s, b = *(const v4f*)(s + 4);
  v8bf o;
#pragma unroll
  for (int j = 0; j < 4; j++) { o[j] = (bf16_t)a[j]; o[4 + j] = (bf16_t)b[j]; }
  *(v8bf*)(dst + (size_t)seg * 1048576 + off) = o;
}

__device__ __forceinline__ void cvt_chunk(const float* __restrict__ s,
                                          bf16_t* __restrict__ d, size_t chunk)
{
  const size_t i = chunk * 8;
  v4f a = *(const v4f*)(s + i), b = *(const v4f*)(s + i + 4);
  v8bf o;
#pragma unroll
  for (int j = 0; j < 4; j++) { o[j] = (bf16_t)a[j]; o[4 + j] = (bf16_t)b[j]; }
  *(v8bf*)(d + i) = o;
}

// k,v f32 -> bf16. 2048 blocks x 256 threads; 4 independent chunks per tensor
// per thread, fully unrolled (deep MLP streamer).
__global__ __launch_bounds__(256) void convert_kv_kernel(
    const float* __restrict__ k, const float* __restrict__ v,
    bf16_t* __restrict__ kb, bf16_t* __restrict__ vb)
{
  const size_t t = (size_t)blockIdx.x * 256 + threadIdx.x;   // 0..524287
#pragma unroll
  for (int j = 0; j < 4; j++) cvt_chunk(k, kb, t + (size_t)j * 524288);
#pragma unroll
  for (int j = 0; j < 4; j++) cvt_chunk(v, vb, t + (size_t)j * 524288);
}

// q f32 -> bf16. 2048 blocks; 4 chunks/thread.
__global__ __launch_bounds__(256) void convert_q_kernel(
    const float* __restrict__ q, bf16_t* __restrict__ qb)
{
  const size_t t = (size_t)blockIdx.x * 256 + threadIdx.x;
#pragma unroll
  for (int j = 0; j < 4; j++) cvt_chunk(q, qb, t + (size_t)j * 524288);
}

// rs[o] = -1e9 * sum_e W[o,e] + b[o]; rows 0..1023 = Wq/bq, 1024..2047 = Wk/bk (f32).
__global__ __launch_bounds__(256) void rowsum_kernel(
    const float* __restrict__ Wq, const float* __restrict__ bq,
    const float* __restrict__ Wk, const float* __restrict__ bk,
    float* __restrict__ rs)
{
  int w = threadIdx.x >> 6, l = threadIdx.x & 63;
  int row = blockIdx.x * 4 + w;
  int r = (row < 1024) ? row : row - 1024;
  const float* W = ((row < 1024) ? Wq : Wk) + (size_t)r * 1024 + l * 16;
  float s = 0.f;
#pragma unroll
  for (int i = 0; i < 4; i++) {
    v4f x = *(const v4f*)(W + i * 4);
    s += x[0] + x[1] + x[2] + x[3];
  }
#pragma unroll
  for (int sh = 1; sh < 64; sh <<= 1) s += __shfl_xor(s, sh, 64);
  if (l == 0) {
    float b = (row < 1024) ? bq[r] : bk[r];
    rs[row] = -1e9f * s + b;
  }
}

// C[m,n] = sum_k A[m,k]*W[n,k] + bias[n], A bf16 (M=16384, N=K=1024), 128x128
// tiles, double-buffered async staging (round-7 proven: 69.2us/497TF on this
// shape). XCD swizzle co-locates the 8 col-tiles of one A row-panel on one
// XCD. EPI 0: plain, masked row -> bias. EPI 1: per-head softmax, masked
// row -> softmax(rs). EPI 2: masked row -> 0, f32 out.
template <int EPI>
__global__ __launch_bounds__(256) void gemm_bt(
    const bf16_t* __restrict__ A, const bf16_t* __restrict__ Wb,
    const float* __restrict__ bias, const int* __restrict__ rowmask,
    const float* __restrict__ rs, void* __restrict__ Cout)
{
  constexpr int K = 1024, N = 1024;
  __shared__ __align__(16) bf16_t As[2][128 * 32];
  __shared__ __align__(16) bf16_t Bs[2][128 * 32];
  const int t = threadIdx.x;
  const int l = t & 63;
  const int w = t >> 6;
  const int wm = w >> 1, wn = w & 1;
  // XCD-aware remap: 8 col-tiles of one A row-panel -> same XCD, consecutive
  const int xcd = blockIdx.x & 7;
  const int seq = blockIdx.x >> 3;
  const int by = ((seq >> 3) << 3) + xcd;   // 0..127
  const int bx = seq & 7;                   // 0..7
  const int m0 = by << 7, n0 = bx << 7;

  const int c0 = t, c1 = t + 256;           // chunk -> row c>>2, k-off (c&3)*8
  const bf16_t* Ag0 = A + (size_t)(m0 + (c0 >> 2)) * K + (c0 & 3) * 8;
  const bf16_t* Ag1 = A + (size_t)(m0 + (c1 >> 2)) * K + (c1 & 3) * 8;
  const bf16_t* Bg0 = Wb + (size_t)(n0 + (c0 >> 2)) * K + (c0 & 3) * 8;
  const bf16_t* Bg1 = Wb + (size_t)(n0 + (c1 >> 2)) * K + (c1 & 3) * 8;

  const int lr = l & 15;
  const int kq = (l >> 4) * 8;
  const int aOff = (wm * 64 + lr) * 32 + kq;
  const int bOff = (wn * 64 + lr) * 32 + kq;

  v4f acc[4][4] = {};

  auto stage = [&](int kt, int b) {
    gl_lds16(Ag0 + kt, &As[b][c0 * 8]);
    gl_lds16(Ag1 + kt, &As[b][c1 * 8]);
    gl_lds16(Bg0 + kt, &Bs[b][c0 * 8]);
    gl_lds16(Bg1 + kt, &Bs[b][c1 * 8]);
  };
  auto compute = [&](const bf16_t* Asb, const bf16_t* Bsb) {
    v8bf af[4], bf4[4];
#pragma unroll
    for (int r = 0; r < 4; r++) af[r] = *(const v8bf*)(Asb + aOff + r * 512);
#pragma unroll
    for (int c = 0; c < 4; c++) bf4[c] = *(const v8bf*)(Bsb + bOff + c * 512);
#pragma unroll
    for (int r = 0; r < 4; r++)
#pragma unroll
      for (int c = 0; c < 4; c++)
        acc[r][c] = __builtin_amdgcn_mfma_f32_16x16x32_bf16(af[r], bf4[c], acc[r][c], 0, 0, 0);
  };

  stage(0, 0);
  for (int kt = 0; kt < K; kt += 64) {
    __syncthreads();                       // drains buf0 loads (in flight during prev compute)
    if (kt + 32 < K) stage(kt + 32, 1);    // prefetch -> buf1
    compute(As[0], Bs[0]);
    __syncthreads();                       // drains buf1 loads
    if (kt + 64 < K) stage(kt + 64, 0);    // prefetch -> buf0
    compute(As[1], Bs[1]);
  }

  // epilogue: C/D layout col = l&15, row = (l>>4)*4 + i
  const int rq = (l >> 4) * 4;
  float bcol[4], rscol[4]; int colg[4];
#pragma unroll
  for (int c = 0; c < 4; c++) {
    colg[c] = n0 + wn * 64 + c * 16 + lr;
    bcol[c] = bias[colg[c]];
    rscol[c] = (EPI == 1) ? rs[colg[c]] : 0.f;
  }
#pragma unroll
  for (int r = 0; r < 4; r++) {
    int rowBase = m0 + wm * 64 + r * 16 + rq;
#pragma unroll
    for (int i = 0; i < 4; i++) {
      int row = rowBase + i;
      int msk = rowmask[row];
      float vv[4];
#pragma unroll
      for (int c = 0; c < 4; c++) {
        float x = acc[r][c][i] + bcol[c];
        if (EPI == 0)      x = msk ? x : bcol[c];
        else if (EPI == 1) x = msk ? x : rscol[c];
        else               x = msk ? x : 0.f;
        vv[c] = x;
      }
      if (EPI == 1) {  // per-head softmax: 64 vals in this 16-lane group x 4 tiles
        float mx = fmaxf(fmaxf(vv[0], vv[1]), fmaxf(vv[2], vv[3]));
#pragma unroll
        for (int sh = 1; sh < 16; sh <<= 1) mx = fmaxf(mx, __shfl_xor(mx, sh, 64));
        float e0 = __expf(vv[0] - mx), e1 = __expf(vv[1] - mx);
        float e2 = __expf(vv[2] - mx), e3 = __expf(vv[3] - mx);
        float sum = e0 + e1 + e2 + e3;
#pragma unroll
        for (int sh = 1; sh < 16; sh <<= 1) sum += __shfl_xor(sum, sh, 64);
        float rinv = 1.0f / sum;
        vv[0] = e0 * rinv; vv[1] = e1 * rinv; vv[2] = e2 * rinv; vv[3] = e3 * rinv;
      }
#pragma unroll
      for (int c = 0; c < 4; c++) {
        size_t idx = (size_t)row * N + colg[c];
        if (EPI == 2) ((float*)Cout)[idx] = vv[c];
        else          ((bf16_t*)Cout)[idx] = (bf16_t)vv[c];
      }
    }
  }
}

// ctx[bh][d][e] += sum_s kh[s][d]*vh[s][e]; kc[bh][d] += sum_s kh[s][d].
// MFMA version (verified round 7). Operands staged TRANSPOSED in f32 LDS
// [64][36] with s-group XOR swizzle; kc via all-ones B-fragment MFMA.
__global__ __launch_bounds__(256) void ctx_partial(
    const bf16_t* __restrict__ kh, const bf16_t* __restrict__ vh,
    float* __restrict__ ctx, float* __restrict__ kc)
{
  __shared__ __align__(16) float khTf[2][64][36];
  __shared__ __align__(16) float vhTf[2][64][36];
  const int bh = blockIdx.x & 63;
  const int sp = blockIdx.x >> 6;
  const int b = bh >> 4, h = bh & 15;
  const int t = threadIdx.x;
  const int l = t & 63;
  const int w = t >> 6;
  const int wm = w >> 1, wn = w & 1;

  const int a  = t & 7;          // d-octet
  const int d0 = a * 8;
  const int sl = t >> 3;         // s within 32-chunk
  const int sw = sl ^ (a << 2);  // swizzled s-column

  const size_t base = ((size_t)b * 4096) * 1024 + h * 64;
  const int sBeg = sp * (4096 / NSPLIT);
  const int nch = (4096 / NSPLIT) / 32;   // 8 chunks of 32 rows
  const bf16_t* kp = kh + base + (size_t)(sBeg + sl) * 1024 + d0;
  const bf16_t* vp = vh + base + (size_t)(sBeg + sl) * 1024 + d0;

  const int lr = l & 15;
  const int gl = l >> 4;         // k-group 0..3

  v8bf ones;
#pragma unroll
  for (int j = 0; j < 8; j++) ones[j] = (bf16_t)1.0f;

  v4f acc[2][2] = {};
  v4f kca[2] = {};

  auto loadfrag = [&](const float (*T)[36], int rowbase) -> v8bf {
    const int row = rowbase + lr;
    const float* rp = &T[row][0];
    const int g0 = ((gl << 1) ^ (row >> 3)) & 7;
    v4f pa = *(const v4f*)(rp + g0 * 4);
    v4f pb = *(const v4f*)(rp + (g0 ^ 1) * 4);
    v8bf f;
#pragma unroll
    for (int j = 0; j < 4; j++) { f[j] = (bf16_t)pa[j]; f[4 + j] = (bf16_t)pb[j]; }
    return f;
  };

  v8bf rk = *(const v8bf*)kp;
  v8bf rv = *(const v8bf*)vp;
  for (int c = 0; c < nch; c++) {
    const int cur = c & 1;
#pragma unroll
    for (int j = 0; j < 8; j++) {
      khTf[cur][d0 + j][sw] = (float)rk[j];
      vhTf[cur][d0 + j][sw] = (float)rv[j];
    }
    if (c + 1 < nch) {
      rk = *(const v8bf*)(kp + (size_t)(c + 1) * 32 * 1024);
      rv = *(const v8bf*)(vp + (size_t)(c + 1) * 32 * 1024);
    }
    __syncthreads();
    v8bf af0 = loadfrag(khTf[cur], wm * 32);
    v8bf af1 = loadfrag(khTf[cur], wm * 32 + 16);
    v8bf bf0 = loadfrag(vhTf[cur], wn * 32);
    v8bf bf1 = loadfrag(vhTf[cur], wn * 32 + 16);
    acc[0][0] = __builtin_amdgcn_mfma_f32_16x16x32_bf16(af0, bf0, acc[0][0], 0, 0, 0);
    acc[0][1] = __builtin_amdgcn_mfma_f32_16x16x32_bf16(af0, bf1, acc[0][1], 0, 0, 0);
    acc[1][0] = __builtin_amdgcn_mfma_f32_16x16x32_bf16(af1, bf0, acc[1][0], 0, 0, 0);
    acc[1][1] = __builtin_amdgcn_mfma_f32_16x16x32_bf16(af1, bf1, acc[1][1], 0, 0, 0);
    if (wn == 0) {
      kca[0] = __builtin_amdgcn_mfma_f32_16x16x32_bf16(af0, ones, kca[0], 0, 0, 0);
      kca[1] = __builtin_amdgcn_mfma_f32_16x16x32_bf16(af1, ones, kca[1], 0, 0, 0);
    }
    __syncthreads();
  }

  const int rq = gl * 4;
  float* cp = ctx + (size_t)bh * 4096;
#pragma unroll
  for (int r = 0; r < 2; r++)
#pragma unroll
    for (int cc = 0; cc < 2; cc++) {
      const int e = wn * 32 + cc * 16 + lr;
#pragma unroll
      for (int i = 0; i < 4; i++) {
        const int d = wm * 32 + r * 16 + rq + i;
        atomicAdd(&cp[d * 64 + e], acc[r][cc][i]);
      }
    }
  if (wn == 0 && lr == 0) {
#pragma unroll
    for (int r = 0; r < 2; r++)
#pragma unroll
      for (int i = 0; i < 4; i++) {
        const int d = wm * 32 + r * 16 + rq + i;
        atomicAdd(&kc[bh * 64 + d], kca[r][i]);
      }
  }
}

// outp = (qh @ ctx) / (qh . kc) + qh   per (b,h); IN-PLACE safe (outp==qh):
// each block stages its full 128x64 chunk into LDS before any global write.
// Grid: 2048 blocks = 4b x 16h x 32 row-chunks of 128 rows.
__global__ __launch_bounds__(256) void outpre_kernel(
    const bf16_t* __restrict__ qh, const float* __restrict__ ctx,
    const float* __restrict__ kc, bf16_t* __restrict__ outp)
{
  __shared__ __align__(16) bf16_t qs[128][66];
  __shared__ __align__(16) float ctxs[64][64];
  __shared__ float kcs[64];
  const int blk = blockIdx.x;
  const int st = blk & 31, h = (blk >> 5) & 15, b = blk >> 9;
  const int bh = b * 16 + h;
  const int t = threadIdx.x;
  const int s0 = st * 128;
  const size_t base = ((size_t)b * 4096 + s0) * 1024 + h * 64;

  {
    const int row = t >> 1, half = t & 1;
    const bf16_t* src = qh + base + (size_t)row * 1024 + half * 32;
#pragma unroll
    for (int j = 0; j < 4; j++) {
      v8bf qv = *(const v8bf*)(src + j * 8);
      uint32_t wv[4];
      __builtin_memcpy(wv, &qv, 16);
      uint32_t* pw = (uint32_t*)&qs[row][half * 32 + j * 8];
      pw[0] = wv[0]; pw[1] = wv[1]; pw[2] = wv[2]; pw[3] = wv[3];
    }
  }
  const float* cg = ctx + (size_t)bh * 4096;
#pragma unroll
  for (int i = 0; i < 4; i++) {
    int off = i * 1024 + t * 4;
    *(v4f*)((float*)ctxs + off) = *(const v4f*)(cg + off);
  }
  if (t < 64) kcs[t] = kc[bh * 64 + t];
  __syncthreads();

  const int er = t & 3, e0 = er * 16;
  const int rp = t >> 2;
  const int r0 = rp * 2;
  float at[2] = {};
  float acc[2][16] = {};
  for (int d = 0; d < 64; d++) {
    const float kcd = kcs[d];
    const float q0 = (float)qs[r0][d];
    const float q1 = (float)qs[r0 + 1][d];
    at[0] += q0 * kcd;
    at[1] += q1 * kcd;
    const float* cr = &ctxs[d][e0];
    v4f ca = *(const v4f*)cr,        cb = *(const v4f*)(cr + 4);
    v4f cc3 = *(const v4f*)(cr + 8), cd4 = *(const v4f*)(cr + 12);
#pragma unroll
    for (int i = 0; i < 4; i++) {
      acc[0][i]      += q0 * ca[i];   acc[1][i]      += q1 * ca[i];
      acc[0][4 + i]  += q0 * cb[i];   acc[1][4 + i]  += q1 * cb[i];
      acc[0][8 + i]  += q0 * cc3[i];  acc[1][8 + i]  += q1 * cc3[i];
      acc[0][12 + i] += q0 * cd4[i];  acc[1][12 + i] += q1 * cd4[i];
    }
  }
#pragma unroll
  for (int j = 0; j < 2; j++) {
    const int row = r0 + j;
    const float rinv = 1.0f / at[j];
    bf16_t* op = outp + base + (size_t)row * 1024 + e0;
    v8bf o0, o1;
#pragma unroll
    for (int i = 0; i < 8; i++) {
      o0[i] = (bf16_t)(acc[j][i] * rinv + (float)qs[row][e0 + i]);
      o1[i] = (bf16_t)(acc[j][8 + i] * rinv + (float)qs[row][e0 + 8 + i]);
    }
    *(v8bf*)op = o0;
    *(v8bf*)(op + 8) = o1;
  }
}

extern "C" void kernel_launch(void* const* d_in, const int* in_sizes, int n_in,
                              void* d_out, int out_size, void* d_ws, size_t ws_size,
                              hipStream_t stream)
{
  const float* q  = (const float*)d_in[0];
  const float* k  = (const float*)d_in[1];
  const float* v  = (const float*)d_in[2];
  const int* qmask = (const int*)d_in[3];
  const int* kmask = (const int*)d_in[4];
  const float* Wq = (const float*)d_in[5];
  const float* bq = (const float*)d_in[6];
  const float* Wk = (const float*)d_in[7];
  const float* bk = (const float*)d_in[8];
  const float* Wv = (const float*)d_in[9];
  const float* bv = (const float*)d_in[10];
  const float* Wp = (const float*)d_in[11];
  const float* bp = (const float*)d_in[12];

  const int M = 16384;
  char* ws = (char*)d_ws;
  size_t off = 0;
  auto alloc = [&](size_t bytes) {
    void* p = ws + off; off += (bytes + 255) & ~(size_t)255; return p;
  };
  bf16_t* wb   = (bf16_t*)alloc(4 * 1048576 * 2);           // 8 MB: Wq,Wk,Wv,Wp bf16
  bf16_t* abuf = (bf16_t*)alloc((size_t)M * 1024 * 2);      // 33.5 MB: kh -> qh -> outp
  float* ctx   = (float*)alloc((64 * 4096 + 64 * 64) * 4);  // 1.06 MB: ctx + kc
  float* kc    = ctx + 64 * 4096;
  float* rs    = (float*)alloc(2048 * 4);
  bf16_t* Wqb = wb, *Wkb = wb + 1048576, *Wvb = wb + 2097152, *Wpb = wb + 3145728;
  // d_out (67 MB f32) as scratch: lo = kb -> vh ; hi = vb -> qb ; final f32 C last
  bf16_t* lo = (bf16_t*)d_out;
  bf16_t* hi = (bf16_t*)((char*)d_out + 33554432);

  hipMemsetAsync(ctx, 0, (64 * 4096 + 64 * 64) * 4, stream);
  convert_w<<<2048, 256, 0, stream>>>(Wq, Wk, Wv, Wp, wb);
  rowsum_kernel<<<512, 256, 0, stream>>>(Wq, bq, Wk, bk, rs);
  convert_kv_kernel<<<2048, 256, 0, stream>>>(k, v, lo, hi);      // kb=lo, vb=hi

  const int gblocks = (M / 128) * (1024 / 128);  // 1024
  gemm_bt<1><<<gblocks, 256, 0, stream>>>(lo, Wkb, bk, kmask, rs + 1024, abuf); // kh
  gemm_bt<0><<<gblocks, 256, 0, stream>>>(hi, Wvb, bv, kmask, nullptr, lo);     // vh (kb dead)
  ctx_partial<<<64 * NSPLIT, 256, 0, stream>>>(abuf, lo, ctx, kc);
  convert_q_kernel<<<2048, 256, 0, stream>>>(q, hi);              // qb (vb dead)
  gemm_bt<1><<<gblocks, 256, 0, stream>>>(hi, Wqb, bq, qmask, rs, abuf);        // qh (kh dead)
  outpre_kernel<<<2048, 256, 0, stream>>>(abuf, ctx, kc, abuf);   // in-place -> outp
  gemm_bt<2><<<gblocks, 256, 0, stream>>>(abuf, Wpb, bp, qmask, nullptr, d_out);
}

// Round 9
// 435.969 us; speedup vs baseline: 1.2275x; 1.2275x over previous
//
#include <hip/hip_runtime.h>
#include <hip/hip_bf16.h>
#include <stdint.h>

// LinearAttention_9569187136035 — round 13: fuse f32->bf16 conversion of the
// activations INTO gemm_bt's A-staging (template AF32: reg-stage A as f32,
// cvt, ds_write to the same swizzled LDS layout; B stays global_load_lds
// bf16). Deletes convert_kv/convert_q entirely (201 MB of pass traffic + the
// measured convert<->gemm cache coupling). Base = round-11 8-phase 256²
// (wall-best family: 467-469 vs 524-535 for 128²). gemm4 (bf16 A) uses AF32=0
// = round-11 path. ctx_partial/outpre/convert_w/rowsum unchanged.

typedef __bf16 bf16_t;
typedef __bf16 v8bf __attribute__((ext_vector_type(8)));
typedef __bf16 v4bf __attribute__((ext_vector_type(4)));
typedef float  v4f  __attribute__((ext_vector_type(4)));

#define NSPLIT 16

__device__ __forceinline__ void gl_lds16(const void* g, void* l) {
  __builtin_amdgcn_global_load_lds((const __attribute__((address_space(1))) void*)g,
                                   (__attribute__((address_space(3))) void*)l,
                                   16, 0, 0);
}

// ---- weights f32 -> bf16 (Wq,Wk,Wv,Wp -> 8MB ws region) ----
__global__ __launch_bounds__(256) void convert_w(
    const float* __restrict__ W0, const float* __restrict__ W1,
    const float* __restrict__ W2, const float* __restrict__ W3,
    bf16_t* __restrict__ dst)
{
  int g = blockIdx.x * 256 + threadIdx.x;      // 2048 blocks
  int seg = g >> 17;
  int off = (g & 131071) * 8;
  const float* s = (seg == 0 ? W0 : seg == 1 ? W1 : seg == 2 ? W2 : W3) + off;
  v4f a = *(const v4f*)s, b = *(const v4f*)(s + 4);
  v8bf o;
#pragma unroll
  for (int j = 0; j < 4; j++) { o[j] = (bf16_t)a[j]; o[4 + j] = (bf16_t)b[j]; }
  *(v8bf*)(dst + (size_t)seg * 1048576 + off) = o;
}

// rs[o] = -1e9 * sum_e W[o,e] + b[o]; rows 0..1023 = Wq/bq, 1024..2047 = Wk/bk (f32).
__global__ __launch_bounds__(256) void rowsum_kernel(
    const float* __restrict__ Wq, const float* __restrict__ bq,
    const float* __restrict__ Wk, const float* __restrict__ bk,
    float* __restrict__ rs)
{
  int w = threadIdx.x >> 6, l = threadIdx.x & 63;
  int row = blockIdx.x * 4 + w;
  int r = (row < 1024) ? row : row - 1024;
  const float* W = ((row < 1024) ? Wq : Wk) + (size_t)r * 1024 + l * 16;
  float s = 0.f;
#pragma unroll
  for (int i = 0; i < 4; i++) {
    v4f x = *(const v4f*)(W + i * 4);
    s += x[0] + x[1] + x[2] + x[3];
  }
#pragma unroll
  for (int sh = 1; sh < 64; sh <<= 1) s += __shfl_xor(s, sh, 64);
  if (l == 0) {
    float b = (row < 1024) ? bq[r] : bk[r];
    rs[row] = -1e9f * s + b;
  }
}

// C[m,n] = sum_k A[m,k]*W[n,k] + bias[n] (M=16384, N=K=1024).
// 256x256 tile, BK=64, 512 threads = 8 waves (2M x 4N). LDS 128KB 2-dbuf.
// Chunk swizzle: LDS slot (row, t&7) holds global chunk (t&7)^(row&7).
// AF32=1: A is f32 in global; staged via reg (8x global_load_dwordx4 issued
// at q1, cvt + 4x ds_write_b128 at tile end, lgkmcnt(0) before boundary
// barrier). AF32=0: A is bf16, global_load_lds (round-11 proven path).
// B always bf16 via global_load_lds; vmcnt(4) counted prefetch (B(s+2) in
// flight across the boundary). XCD swizzle co-locates the 4 col-blocks of
// one A row-panel on one XCD (round-11: FETCH 68->25MB).
// EPI 0: plain, masked row -> bias. EPI 1: per-head softmax, masked row ->
// softmax(rs). EPI 2: masked row -> 0, f32 out.
template <int EPI, int AF32>
__global__ __launch_bounds__(512, 2) void gemm_bt(
    const void* __restrict__ Ax, const bf16_t* __restrict__ Wb,
    const float* __restrict__ bias, const int* __restrict__ rowmask,
    const float* __restrict__ rs, void* __restrict__ Cout)
{
  constexpr int K = 1024, N = 1024;
  constexpr int NT = 16;                    // K-tiles of 64
  __shared__ __align__(16) bf16_t As[2][256 * 64];
  __shared__ __align__(16) bf16_t Bs[2][256 * 64];
  const int t = threadIdx.x;
  const int l = t & 63;
  const int w = t >> 6;                     // 0..7
  const int wm = w >> 2, wn = w & 3;        // 2 x 4 wave grid
  // XCD-aware remap: XCD x owns row-panels by = x*8..x*8+7, all 4 col-panels.
  const int xcd = blockIdx.x & 7, seq = blockIdx.x >> 3;
  const int by = xcd * 8 + (seq & 7), bx = seq >> 3;
  const int m0 = by << 8, n0 = bx << 8;

  // staging coords: LDS slot (row srow+r*64, gslot=t&7) <- global chunk
  // gslot ^ (srow&7), i.e. global column sgs*8.
  const int srow = t >> 3;                  // 0..63
  const int sgs  = (t & 7) ^ (srow & 7);
  const bf16_t* Ag = (const bf16_t*)Ax + (size_t)(m0 + srow) * K + sgs * 8;
  const float*  Af = (const float*) Ax + (size_t)(m0 + srow) * K + sgs * 8;
  const bf16_t* Bg = Wb + (size_t)(n0 + srow) * K + sgs * 8;
  bf16_t* lA = &As[0][0] + t * 8;
  bf16_t* lB = &Bs[0][0] + t * 8;

  auto stageA = [&](int half, int kt, int buf) {   // AF32==0 path
    const bf16_t* s = Ag + (size_t)(half * 128) * K + (kt << 6);
    bf16_t* d = lA + buf * 16384 + half * 8192;
    gl_lds16(s, d);
    gl_lds16(s + (size_t)64 * K, d + 4096);
  };
  auto stageB = [&](int half, int kt, int buf) {
    const bf16_t* s = Bg + (size_t)(half * 128) * K + (kt << 6);
    bf16_t* d = lB + buf * 16384 + half * 8192;
    gl_lds16(s, d);
    gl_lds16(s + (size_t)64 * K, d + 4096);
  };

  // AF32==1 path: reg-staged A (rows srow + r*64, r=0..3 -> LDS +r*4096)
  v4f ald[4][2];
  auto issueA = [&](int kt) {
#pragma unroll
    for (int r = 0; r < 4; r++) {
      const float* p = Af + (size_t)(r * 64) * K + (kt << 6);
      ald[r][0] = *(const v4f*)p;
      ald[r][1] = *(const v4f*)(p + 4);
    }
  };
  auto writeA = [&](int buf) {
#pragma unroll
    for (int r = 0; r < 4; r++) {
      v8bf o;
#pragma unroll
      for (int j = 0; j < 4; j++) {
        o[j]     = (bf16_t)ald[r][0][j];
        o[4 + j] = (bf16_t)ald[r][1][j];
      }
      *(v8bf*)(lA + buf * 16384 + r * 4096) = o;
    }
  };

  // fragment read offsets (swizzled chunk)
  const int lr = l & 15, kg = l >> 4;
  const int xg0 = ((kg)     ^ (lr & 7)) * 8;
  const int xg1 = ((4 + kg) ^ (lr & 7)) * 8;
  const int aB = (wm * 128 + lr) * 64;
  const int bB = (wn * 64  + lr) * 64;

  v4f acc[8][4] = {};
  v8bf bfr[4][2];

#define QUAD(R0, R1, A0_, A1_, A2_, A3_)                                        \
  {                                                                             \
    __builtin_amdgcn_s_setprio(1);                                              \
    _Pragma("unroll")                                                           \
    for (int c = 0; c < 4; ++c) {                                               \
      acc[R0][c] = __builtin_amdgcn_mfma_f32_16x16x32_bf16(A0_, bfr[c][0], acc[R0][c], 0, 0, 0); \
      acc[R0][c] = __builtin_amdgcn_mfma_f32_16x16x32_bf16(A1_, bfr[c][1], acc[R0][c], 0, 0, 0); \
      acc[R1][c] = __builtin_amdgcn_mfma_f32_16x16x32_bf16(A2_, bfr[c][0], acc[R1][c], 0, 0, 0); \
      acc[R1][c] = __builtin_amdgcn_mfma_f32_16x16x32_bf16(A3_, bfr[c][1], acc[R1][c], 0, 0, 0); \
    }                                                                           \
    __builtin_amdgcn_s_setprio(0);                                              \
  }

  // prologue: K-tile 0 + B(1); A(1) handled at s=0.q1
  if (AF32) issueA(0);
  else { stageA(0, 0, 0); stageA(1, 0, 0); }
  stageB(0, 0, 0); stageB(1, 0, 0);
  stageB(0, 1, 1); stageB(1, 1, 1);
  if (AF32) writeA(0);                               // compiler waits A regs
  asm volatile("s_waitcnt vmcnt(4)" ::: "memory");   // B(0) landed; B(1) flying
  asm volatile("s_waitcnt lgkmcnt(0)" ::: "memory");
  __builtin_amdgcn_s_barrier();

  for (int s = 0; s < NT; ++s) {
    const int b = s & 1;
    const bf16_t* Ab = &As[b][0];
    const bf16_t* Bb = &Bs[b][0];
    v8bf a0, a1, a2, a3;
    // ---- q1: issue A(s+1); B frags + A rows 0,1 ----
    if (s + 1 < NT) {
      if (AF32) issueA(s + 1);
      else { stageA(0, s + 1, b ^ 1); stageA(1, s + 1, b ^ 1); }
    }
#pragma unroll
    for (int c = 0; c < 4; ++c) {
      bfr[c][0] = *(const v8bf*)(Bb + bB + c * 1024 + xg0);
      bfr[c][1] = *(const v8bf*)(Bb + bB + c * 1024 + xg1);
    }
    a0 = *(const v8bf*)(Ab + aB + 0 * 1024 + xg0);
    a1 = *(const v8bf*)(Ab + aB + 0 * 1024 + xg1);
    a2 = *(const v8bf*)(Ab + aB + 1 * 1024 + xg0);
    a3 = *(const v8bf*)(Ab + aB + 1 * 1024 + xg1);
    __builtin_amdgcn_s_barrier();
    QUAD(0, 1, a0, a1, a2, a3);
    __builtin_amdgcn_s_barrier();
    // ---- q2: A rows 2,3 ----
    a0 = *(const v8bf*)(Ab + aB + 2 * 1024 + xg0);
    a1 = *(const v8bf*)(Ab + aB + 2 * 1024 + xg1);
    a2 = *(const v8bf*)(Ab + aB + 3 * 1024 + xg0);
    a3 = *(const v8bf*)(Ab + aB + 3 * 1024 + xg1);
    __builtin_amdgcn_s_barrier();
    QUAD(2, 3, a0, a1, a2, a3);
    __builtin_amdgcn_s_barrier();
    // ---- q3: A rows 4,5; stage B(s+2) -> buf (region free since q1) ----
    a0 = *(const v8bf*)(Ab + aB + 4 * 1024 + xg0);
    a1 = *(const v8bf*)(Ab + aB + 4 * 1024 + xg1);
    a2 = *(const v8bf*)(Ab + aB + 5 * 1024 + xg0);
    a3 = *(const v8bf*)(Ab + aB + 5 * 1024 + xg1);
    if (s + 2 < NT) { stageB(0, s + 2, b); stageB(1, s + 2, b); }
    __builtin_amdgcn_s_barrier();
    QUAD(4, 5, a0, a1, a2, a3);
    __builtin_amdgcn_s_barrier();
    // ---- q4: A rows 6,7; cvt+write A(s+1); counted vmcnt at boundary ----
    a0 = *(const v8bf*)(Ab + aB + 6 * 1024 + xg0);
    a1 = *(const v8bf*)(Ab + aB + 6 * 1024 + xg1);
    a2 = *(const v8bf*)(Ab + aB + 7 * 1024 + xg0);
    a3 = *(const v8bf*)(Ab + aB + 7 * 1024 + xg1);
    __builtin_amdgcn_s_barrier();
    QUAD(6, 7, a0, a1, a2, a3);
    if (AF32 && s + 1 < NT) writeA(b ^ 1);  // buf^1 A region free since last boundary
    if (s < NT - 2) asm volatile("s_waitcnt vmcnt(4)" ::: "memory");
    else            asm volatile("s_waitcnt vmcnt(0)" ::: "memory");
    asm volatile("s_waitcnt lgkmcnt(0)" ::: "memory");  // ds_writes visible
    __builtin_amdgcn_s_barrier();
  }
#undef QUAD

  // epilogue: C/D layout col = l&15, row = (l>>4)*4 + i per 16x16 frag
  const int rq = kg * 4;
  float bcol[4], rscol[4]; int colg[4];
#pragma unroll
  for (int c = 0; c < 4; c++) {
    colg[c] = n0 + wn * 64 + c * 16 + lr;
    bcol[c] = bias[colg[c]];
    rscol[c] = (EPI == 1) ? rs[colg[c]] : 0.f;
  }
#pragma unroll
  for (int r = 0; r < 8; r++) {
    int rowBase = m0 + wm * 128 + r * 16 + rq;
#pragma unroll
    for (int i = 0; i < 4; i++) {
      int row = rowBase + i;
      int msk = rowmask[row];
      float vv[4];
#pragma unroll
      for (int c = 0; c < 4; c++) {
        float x = acc[r][c][i] + bcol[c];
        if (EPI == 0)      x = msk ? x : bcol[c];
        else if (EPI == 1) x = msk ? x : rscol[c];
        else               x = msk ? x : 0.f;
        vv[c] = x;
      }
      if (EPI == 1) {  // per-head softmax: 64 vals in this 16-lane group x 4 tiles
        float mx = fmaxf(fmaxf(vv[0], vv[1]), fmaxf(vv[2], vv[3]));
#pragma unroll
        for (int sh = 1; sh < 16; sh <<= 1) mx = fmaxf(mx, __shfl_xor(mx, sh, 64));
        float e0 = __expf(vv[0] - mx), e1 = __expf(vv[1] - mx);
        float e2 = __expf(vv[2] - mx), e3 = __expf(vv[3] - mx);
        float sum = e0 + e1 + e2 + e3;
#pragma unroll
        for (int sh = 1; sh < 16; sh <<= 1) sum += __shfl_xor(sum, sh, 64);
        float rinv = 1.0f / sum;
        vv[0] = e0 * rinv; vv[1] = e1 * rinv; vv[2] = e2 * rinv; vv[3] = e3 * rinv;
      }
#pragma unroll
      for (int c = 0; c < 4; c++) {
        size_t idx = (size_t)row * N + colg[c];
        if (EPI == 2) ((float*)Cout)[idx] = vv[c];
        else          ((bf16_t*)Cout)[idx] = (bf16_t)vv[c];
      }
    }
  }
}

// ctx[bh][d][e] += sum_s kh[s][d]*vh[s][e]; kc[bh][d] += sum_s kh[s][d].
// MFMA version (verified round 7). Operands staged TRANSPOSED in f32 LDS
// [64][36] with s-group XOR swizzle; kc via all-ones B-fragment MFMA.
__global__ __launch_bounds__(256) void ctx_partial(
    const bf16_t* __restrict__ kh, const bf16_t* __restrict__ vh,
    float* __restrict__ ctx, float* __restrict__ kc)
{
  __shared__ __align__(16) float khTf[2][64][36];
  __shared__ __align__(16) float vhTf[2][64][36];
  const int bh = blockIdx.x & 63;
  const int sp = blockIdx.x >> 6;
  const int b = bh >> 4, h = bh & 15;
  const int t = threadIdx.x;
  const int l = t & 63;
  const int w = t >> 6;
  const int wm = w >> 1, wn = w & 1;

  const int a  = t & 7;          // d-octet
  const int d0 = a * 8;
  const int sl = t >> 3;         // s within 32-chunk
  const int sw = sl ^ (a << 2);  // swizzled s-column

  const size_t base = ((size_t)b * 4096) * 1024 + h * 64;
  const int sBeg = sp * (4096 / NSPLIT);
  const int nch = (4096 / NSPLIT) / 32;   // 8 chunks of 32 rows
  const bf16_t* kp = kh + base + (size_t)(sBeg + sl) * 1024 + d0;
  const bf16_t* vp = vh + base + (size_t)(sBeg + sl) * 1024 + d0;

  const int lr = l & 15;
  const int gl = l >> 4;         // k-group 0..3

  v8bf ones;
#pragma unroll
  for (int j = 0; j < 8; j++) ones[j] = (bf16_t)1.0f;

  v4f acc[2][2] = {};
  v4f kca[2] = {};

  auto loadfrag = [&](const float (*T)[36], int rowbase) -> v8bf {
    const int row = rowbase + lr;
    const float* rp = &T[row][0];
    const int g0 = ((gl << 1) ^ (row >> 3)) & 7;
    v4f pa = *(const v4f*)(rp + g0 * 4);
    v4f pb = *(const v4f*)(rp + (g0 ^ 1) * 4);
    v8bf f;
#pragma unroll
    for (int j = 0; j < 4; j++) { f[j] = (bf16_t)pa[j]; f[4 + j] = (bf16_t)pb[j]; }
    return f;
  };

  v8bf rk = *(const v8bf*)kp;
  v8bf rv = *(const v8bf*)vp;
  for (int c = 0; c < nch; c++) {
    const int cur = c & 1;
#pragma unroll
    for (int j = 0; j < 8; j++) {
      khTf[cur][d0 + j][sw] = (float)rk[j];
      vhTf[cur][d0 + j][sw] = (float)rv[j];
    }
    if (c + 1 < nch) {
      rk = *(const v8bf*)(kp + (size_t)(c + 1) * 32 * 1024);
      rv = *(const v8bf*)(vp + (size_t)(c + 1) * 32 * 1024);
    }
    __syncthreads();
    v8bf af0 = loadfrag(khTf[cur], wm * 32);
    v8bf af1 = loadfrag(khTf[cur], wm * 32 + 16);
    v8bf bf0 = loadfrag(vhTf[cur], wn * 32);
    v8bf bf1 = loadfrag(vhTf[cur], wn * 32 + 16);
    acc[0][0] = __builtin_amdgcn_mfma_f32_16x16x32_bf16(af0, bf0, acc[0][0], 0, 0, 0);
    acc[0][1] = __builtin_amdgcn_mfma_f32_16x16x32_bf16(af0, bf1, acc[0][1], 0, 0, 0);
    acc[1][0] = __builtin_amdgcn_mfma_f32_16x16x32_bf16(af1, bf0, acc[1][0], 0, 0, 0);
    acc[1][1] = __builtin_amdgcn_mfma_f32_16x16x32_bf16(af1, bf1, acc[1][1], 0, 0, 0);
    if (wn == 0) {
      kca[0] = __builtin_amdgcn_mfma_f32_16x16x32_bf16(af0, ones, kca[0], 0, 0, 0);
      kca[1] = __builtin_amdgcn_mfma_f32_16x16x32_bf16(af1, ones, kca[1], 0, 0, 0);
    }
    __syncthreads();
  }

  const int rq = gl * 4;
  float* cp = ctx + (size_t)bh * 4096;
#pragma unroll
  for (int r = 0; r < 2; r++)
#pragma unroll
    for (int cc = 0; cc < 2; cc++) {
      const int e = wn * 32 + cc * 16 + lr;
#pragma unroll
      for (int i = 0; i < 4; i++) {
        const int d = wm * 32 + r * 16 + rq + i;
        atomicAdd(&cp[d * 64 + e], acc[r][cc][i]);
      }
    }
  if (wn == 0 && lr == 0) {
#pragma unroll
    for (int r = 0; r < 2; r++)
#pragma unroll
      for (int i = 0; i < 4; i++) {
        const int d = wm * 32 + r * 16 + rq + i;
        atomicAdd(&kc[bh * 64 + d], kca[r][i]);
      }
  }
}

// outp = (qh @ ctx) / (qh . kc) + qh   per (b,h); IN-PLACE safe (outp==qh):
// each block stages its full 128x64 chunk into LDS before any global write.
// Grid: 2048 blocks = 4b x 16h x 32 row-chunks of 128 rows.
__global__ __launch_bounds__(256) void outpre_kernel(
    const bf16_t* __restrict__ qh, const float* __restrict__ ctx,
    const float* __restrict__ kc, bf16_t* __restrict__ outp)
{
  __shared__ __align__(16) bf16_t qs[128][66];
  __shared__ __align__(16) float ctxs[64][64];
  __shared__ float kcs[64];
  const int blk = blockIdx.x;
  const int st = blk & 31, h = (blk >> 5) & 15, b = blk >> 9;
  const int bh = b * 16 + h;
  const int t = threadIdx.x;
  const int s0 = st * 128;
  const size_t base = ((size_t)b * 4096 + s0) * 1024 + h * 64;

  {
    const int row = t >> 1, half = t & 1;
    const bf16_t* src = qh + base + (size_t)row * 1024 + half * 32;
#pragma unroll
    for (int j = 0; j < 4; j++) {
      v8bf qv = *(const v8bf*)(src + j * 8);
      uint32_t wv[4];
      __builtin_memcpy(wv, &qv, 16);
      uint32_t* pw = (uint32_t*)&qs[row][half * 32 + j * 8];
      pw[0] = wv[0]; pw[1] = wv[1]; pw[2] = wv[2]; pw[3] = wv[3];
    }
  }
  const float* cg = ctx + (size_t)bh * 4096;
#pragma unroll
  for (int i = 0; i < 4; i++) {
    int off = i * 1024 + t * 4;
    *(v4f*)((float*)ctxs + off) = *(const v4f*)(cg + off);
  }
  if (t < 64) kcs[t] = kc[bh * 64 + t];
  __syncthreads();

  const int er = t & 3, e0 = er * 16;
  const int rp = t >> 2;
  const int r0 = rp * 2;
  float at[2] = {};
  float acc[2][16] = {};
  for (int d = 0; d < 64; d++) {
    const float kcd = kcs[d];
    const float q0 = (float)qs[r0][d];
    const float q1 = (float)qs[r0 + 1][d];
    at[0] += q0 * kcd;
    at[1] += q1 * kcd;
    const float* cr = &ctxs[d][e0];
    v4f ca = *(const v4f*)cr,        cb = *(const v4f*)(cr + 4);
    v4f cc3 = *(const v4f*)(cr + 8), cd4 = *(const v4f*)(cr + 12);
#pragma unroll
    for (int i = 0; i < 4; i++) {
      acc[0][i]      += q0 * ca[i];   acc[1][i]      += q1 * ca[i];
      acc[0][4 + i]  += q0 * cb[i];   acc[1][4 + i]  += q1 * cb[i];
      acc[0][8 + i]  += q0 * cc3[i];  acc[1][8 + i]  += q1 * cc3[i];
      acc[0][12 + i] += q0 * cd4[i];  acc[1][12 + i] += q1 * cd4[i];
    }
  }
#pragma unroll
  for (int j = 0; j < 2; j++) {
    const int row = r0 + j;
    const float rinv = 1.0f / at[j];
    bf16_t* op = outp + base + (size_t)row * 1024 + e0;
    v8bf o0, o1;
#pragma unroll
    for (int i = 0; i < 8; i++) {
      o0[i] = (bf16_t)(acc[j][i] * rinv + (float)qs[row][e0 + i]);
      o1[i] = (bf16_t)(acc[j][8 + i] * rinv + (float)qs[row][e0 + 8 + i]);
    }
    *(v8bf*)op = o0;
    *(v8bf*)(op + 8) = o1;
  }
}

extern "C" void kernel_launch(void* const* d_in, const int* in_sizes, int n_in,
                              void* d_out, int out_size, void* d_ws, size_t ws_size,
                              hipStream_t stream)
{
  const float* q  = (const float*)d_in[0];
  const float* k  = (const float*)d_in[1];
  const float* v  = (const float*)d_in[2];
  const int* qmask = (const int*)d_in[3];
  const int* kmask = (const int*)d_in[4];
  const float* Wq = (const float*)d_in[5];
  const float* bq = (const float*)d_in[6];
  const float* Wk = (const float*)d_in[7];
  const float* bk = (const float*)d_in[8];
  const float* Wv = (const float*)d_in[9];
  const float* bv = (const float*)d_in[10];
  const float* Wp = (const float*)d_in[11];
  const float* bp = (const float*)d_in[12];

  const int M = 16384;
  char* ws = (char*)d_ws;
  size_t off = 0;
  auto alloc = [&](size_t bytes) {
    void* p = ws + off; off += (bytes + 255) & ~(size_t)255; return p;
  };
  bf16_t* wb   = (bf16_t*)alloc(4 * 1048576 * 2);           // 8 MB: Wq,Wk,Wv,Wp bf16
  bf16_t* abuf = (bf16_t*)alloc((size_t)M * 1024 * 2);      // 33.5 MB: kh -> qh -> outp
  float* ctx   = (float*)alloc((64 * 4096 + 64 * 64) * 4);  // 1.06 MB: ctx + kc
  float* kc    = ctx + 64 * 4096;
  float* rs    = (float*)alloc(2048 * 4);
  bf16_t* Wqb = wb, *Wkb = wb + 1048576, *Wvb = wb + 2097152, *Wpb = wb + 3145728;
  // d_out (67 MB f32) as scratch: lo = vh (bf16); final f32 C overwrites last
  bf16_t* lo = (bf16_t*)d_out;

  hipMemsetAsync(ctx, 0, (64 * 4096 + 64 * 64) * 4, stream);
  convert_w<<<2048, 256, 0, stream>>>(Wq, Wk, Wv, Wp, wb);
  rowsum_kernel<<<512, 256, 0, stream>>>(Wq, bq, Wk, bk, rs);

  const int gblocks = (M / 256) * (1024 / 256);  // 256
  gemm_bt<1, 1><<<gblocks, 512, 0, stream>>>(k, Wkb, bk, kmask, rs + 1024, abuf); // kh (f32 A)
  gemm_bt<0, 1><<<gblocks, 512, 0, stream>>>(v, Wvb, bv, kmask, nullptr, lo);     // vh (f32 A)
  ctx_partial<<<64 * NSPLIT, 256, 0, stream>>>(abuf, lo, ctx, kc);
  gemm_bt<1, 1><<<gblocks, 512, 0, stream>>>(q, Wqb, bq, qmask, rs, abuf);        // qh (f32 A, kh dead)
  outpre_kernel<<<2048, 256, 0, stream>>>(abuf, ctx, kc, abuf);   // in-place -> outp
  gemm_bt<2, 0><<<gblocks, 512, 0, stream>>>(abuf, Wpb, bp, qmask, nullptr, d_out); // bf16 A
}